// Round 13
// baseline (403.710 us; speedup 1.0000x reference)
//
#include <hip/hip_runtime.h>
#include <hip/hip_fp16.h>

typedef _Float16 f16;
typedef _Float16 f16x8 __attribute__((ext_vector_type(8)));
typedef _Float16 f16x4 __attribute__((ext_vector_type(4)));
typedef float    f32x4 __attribute__((ext_vector_type(4)));

#define MFMA16(a, b, c) __builtin_amdgcn_mfma_f32_16x16x32_f16((a), (b), (c), 0, 0, 0)

#define BARR() __builtin_amdgcn_s_barrier()
#define VMW6() asm volatile("s_waitcnt vmcnt(6)" ::: "memory")
#define VMW4() asm volatile("s_waitcnt vmcnt(4)" ::: "memory")
#define VMW2() asm volatile("s_waitcnt vmcnt(2)" ::: "memory")
#define VMW0() asm volatile("s_waitcnt vmcnt(0)" ::: "memory")
#define LGKM0() asm volatile("s_waitcnt lgkmcnt(0)" ::: "memory")

// global->LDS async, 16B/lane. Offset arg MUST be 0 (R4: imm applies to both
// global AND LDS address) — all offsets via pointer arithmetic.
#define GLOAD16(P, L)                                                          \
  __builtin_amdgcn_global_load_lds(                                            \
      (const __attribute__((address_space(1))) unsigned int*)(P),              \
      (__attribute__((address_space(3))) unsigned int*)(L), 16, 0, 0)

// inverse st_16x32 swizzle: slot s (16B units) of a [R][64]-f16 region -> (row,col)
__device__ __forceinline__ void inv_swz(int s, int& r, int& c) {
  int rel = s * 16;
  int sub = rel >> 10, q = rel & 1023;
  int inner = q ^ (((q >> 9) & 1) << 5);
  r = ((sub >> 1) << 4) + (inner >> 6);
  c = ((sub & 1) << 5) + ((inner & 63) >> 1);
}

// ---------------- f32 -> f16 cast (x) ----------------
__global__ __launch_bounds__(256) void cast_f32_to_f16(const float* __restrict__ src,
                                                       f16* __restrict__ dst, int n4) {
  int i = blockIdx.x * 256 + threadIdx.x;
  if (i >= n4) return;
  float4 v = reinterpret_cast<const float4*>(src)[i];
  f16x4 o = { (f16)v.x, (f16)v.y, (f16)v.z, (f16)v.w };
  reinterpret_cast<f16x4*>(dst)[i] = o;
}

// ---------------- fused weight casts ----------------
__global__ __launch_bounds__(256) void cast_weights(const float* __restrict__ Wq,
                                                    const float* __restrict__ Wk,
                                                    const float* __restrict__ Wv,
                                                    const float* __restrict__ Wo,
                                                    f16* __restrict__ wqkvh,
                                                    f16* __restrict__ woh) {
  const int k = blockIdx.x >> 10;
  const int i = (blockIdx.x & 1023) * 256 + threadIdx.x;
  const float* src = (k == 0) ? Wq : (k == 1) ? Wk : (k == 2) ? Wv : Wo;
  f16* dst = (k == 3) ? woh : (wqkvh + k * 1048576);
  float4 v = reinterpret_cast<const float4*>(src)[i];
  f16x4 o = { (f16)v.x, (f16)v.y, (f16)v.z, (f16)v.w };
  reinterpret_cast<f16x4*>(dst)[i] = o;
}

// ======== QKV GEMM, 12-wave / 3-waves-per-SIMD: C[M,3072] = A * B^T, K=1024 ========
// 256x192 tile, 768 threads = 12 waves (4M x 3N), per-wave 64x64 (acc=64 VGPR ->
// 3 waves/SIMD residency, the occupancy lever). BK=64, 2-buf 112 KiB LDS
// ([A 32K | B 24K] per buf), st_16x32 swizzle, raw barriers.
// 2 phases/tile: p1{read af+bf(nh0); stage B(T+1); BARR; LGKM0; 16 MFMA},
//                p2{read bf(nh1);    stage A(T+2); BARR; LGKM0; 16 MFMA; gate}.
// A-staging = 2 uniform ops + 2 ops on waves 8-11 only (slot remainder), so the
// counted gates are per-wave: VMW2 (w0-7) / VMW4 (w8-11).
__global__ __launch_bounds__(768, 3) void gemm_qkv_12w(const f16* __restrict__ A,
                                                       const f16* __restrict__ B,
                                                       f16* __restrict__ C,
                                                       int N, int nbx) {
  constexpr int K = 1024;
  __shared__ f16 lds[2][28672];   // [buf][ A:16384 f16 | B:12288 f16 ]

  const int tid = threadIdx.x;
  const int wid = tid >> 6, l = tid & 63;
  const int wr = wid & 3;          // M group (64 rows)
  const int wc = wid >> 2;         // N group (64 cols), 0..2

  // T1: bijective XCD swizzle (nwg % 8 == 0); bx fast within XCD chunk
  const int nwg = gridDim.x;
  const int cpx = nwg >> 3;
  const int id = blockIdx.x;
  const int swz = (id & 7) * cpx + (id >> 3);
  const int bx = swz % nbx, by = swz / nbx;

  // staging source coords
  int rAa, cAa, rAb, cAb, rB, cB;
  inv_swz(tid, rAa, cAa);                    // A half-region [128][64], slots 0..767
  inv_swz(768 + (tid & 255), rAb, cAb);      // A half-region slots 768..1023 (w8-11)
  inv_swz(tid, rB, cB);                      // B half-region [96][64], slots 0..767

  const f16* gAa = A + (size_t)(by * 256 + rAa) * K + cAa;   // + h*128*K
  const f16* gAb = A + (size_t)(by * 256 + rAb) * K + cAb;
  const f16* gB0 = B + (size_t)(bx * 192 + rB) * K + cB;
  const f16* gB1 = gB0 + 96 * K;

  // A(T) -> lds[buf][0..16384); halves 8192 f16 each; op_a covers f16 [0,6144),
  // op_b (w8-11) covers [6144,8192). B -> lds[buf][16384..); halves 6144 f16.
#define STAGE_A(bufb, EOFF)                                                    \
  { GLOAD16(gAa + (EOFF), &lds[bufb][0] + wid * 512);                          \
    GLOAD16(gAa + 128 * K + (EOFF), &lds[bufb][8192] + wid * 512);             \
    if (wid >= 8) {                                                            \
      GLOAD16(gAb + (EOFF), &lds[bufb][6144] + (wid - 8) * 512);               \
      GLOAD16(gAb + 128 * K + (EOFF), &lds[bufb][8192 + 6144] + (wid - 8) * 512); \
    } }
#define STAGE_B(bufb, EOFF)                                                    \
  { GLOAD16(gB0 + (EOFF), &lds[bufb][16384] + wid * 512);                      \
    GLOAD16(gB1 + (EOFF), &lds[bufb][16384 + 6144] + wid * 512); }

  const int lane_rd = (((l & 15) << 6) + ((l >> 4) << 4)) ^ (((l >> 3) & 1) << 5);
  const char* rdA0 = (const char*)&lds[0][0] + lane_rd;
  const char* rdA1 = (const char*)&lds[1][0] + lane_rd;
  const char* rdB0 = (const char*)&lds[0][16384] + lane_rd;
  const char* rdB1 = (const char*)&lds[1][16384] + lane_rd;

  f16x8 af[4][2], bf[2][2];
  f32x4 acc[4][4] = {};

#define READ_AF(RD)                                                            \
  _Pragma("unroll") for (int mt = 0; mt < 4; ++mt)                             \
  _Pragma("unroll") for (int ks = 0; ks < 2; ++ks)                             \
    af[mt][ks] = *reinterpret_cast<const f16x8*>(                              \
        (RD) + ((((wr * 4 + mt) * 2) + ks) << 10));
#define READ_BF(RD, nh)                                                        \
  _Pragma("unroll") for (int nt = 0; nt < 2; ++nt)                             \
  _Pragma("unroll") for (int ks = 0; ks < 2; ++ks)                             \
    bf[nt][ks] = *reinterpret_cast<const f16x8*>(                              \
        (RD) + ((((wc * 4 + (nh) * 2 + nt) * 2) + ks) << 10));
#define CL(nh)                                                                 \
  __builtin_amdgcn_s_setprio(1);                                               \
  _Pragma("unroll") for (int mt = 0; mt < 4; ++mt)                             \
  _Pragma("unroll") for (int nt = 0; nt < 2; ++nt)                             \
  _Pragma("unroll") for (int ks = 0; ks < 2; ++ks)                             \
    acc[mt][(nh) * 2 + nt] = MFMA16(af[mt][ks], bf[nt][ks], acc[mt][(nh) * 2 + nt]); \
  __builtin_amdgcn_s_setprio(0);

  // prologue: tile0 -> buf0, tile1 -> buf1; leave tile1 in flight
  STAGE_A(0, 0); STAGE_B(0, 0);
  STAGE_A(1, 64); STAGE_B(1, 64);
  if (wid < 8) { VMW4(); } else { VMW6(); }   // tile0 landed
  BARR();

  for (int i = 0; i < 8; ++i) {
    const bool more = (i < 7);
    // p1(2i): buf0
    READ_AF(rdA0); READ_BF(rdB0, 0);
    STAGE_B(1, 64);                       // B(2i+1) -> buf1
    BARR(); LGKM0(); CL(0); BARR();
    // p2(2i)
    READ_BF(rdB0, 1);
    if (more) STAGE_A(0, 128);            // A(2i+2) -> buf0 (A read done p1)
    BARR(); LGKM0(); CL(1);
    if (more) { if (wid < 8) { VMW2(); } else { VMW4(); } } else { VMW0(); }
    BARR();                               // tile 2i+1 ready
    // p1(2i+1): buf1
    READ_AF(rdA1); READ_BF(rdB1, 0);
    if (more) STAGE_B(0, 128);            // B(2i+2) -> buf0 (B reads done p2)
    BARR(); LGKM0(); CL(0); BARR();
    // p2(2i+1)
    READ_BF(rdB1, 1);
    if (more) STAGE_A(1, 192);            // A(2i+3) -> buf1
    BARR(); LGKM0(); CL(1);
    if (more) { if (wid < 8) { VMW2(); } else { VMW4(); } }
    BARR();                               // tile 2i+2 ready
    gAa += 128; gAb += 128; gB0 += 128; gB1 += 128;
  }

  const int rr = by * 256 + wr * 64 + ((l >> 4) << 2);
  const int cc = bx * 192 + wc * 64 + (l & 15);
#pragma unroll
  for (int mt = 0; mt < 4; ++mt)
#pragma unroll
    for (int ntg = 0; ntg < 4; ++ntg)
#pragma unroll
      for (int j = 0; j < 4; ++j)
        C[(size_t)(rr + mt * 16 + j) * N + cc + ntg * 16] = (f16)acc[mt][ntg][j];
#undef STAGE_A
#undef STAGE_B
#undef READ_AF
#undef READ_BF
#undef CL
}

// ============ 256x256 8-phase GEMM (proj): C[M,N] = A[M,K] * B[N,K]^T ============
template <typename OutT>
__global__ __launch_bounds__(512, 1) void gemm_bt_8ph(const f16* __restrict__ A,
                                                      const f16* __restrict__ B,
                                                      OutT* __restrict__ C,
                                                      int N, int nbx) {
  constexpr int K = 1024;
  __shared__ f16 lds[2][2][2][8192];   // [buf][A/B][half][16KB]

  const int tid = threadIdx.x;
  const int wid = tid >> 6, l = tid & 63;
  const int wr = wid >> 2, wc = wid & 3;

  const int nwg = gridDim.x;
  const int cpx = nwg >> 3;
  const int id = blockIdx.x;
  const int swz = (id & 7) * cpx + (id >> 3);
  const int bx = swz % nbx, by = swz / nbx;

  int r0s, c0s, r1s, c1s;
  inv_swz(tid, r0s, c0s);
  inv_swz(512 + tid, r1s, c1s);
  const f16* gA0a = A + (size_t)(by * 256 + r0s) * K + c0s;
  const f16* gA0b = A + (size_t)(by * 256 + r1s) * K + c1s;
  const f16* gA1a = gA0a + 128 * K;
  const f16* gA1b = gA0b + 128 * K;
  const f16* gB0a = B + (size_t)(bx * 256 + r0s) * K + c0s;
  const f16* gB0b = B + (size_t)(bx * 256 + r1s) * K + c1s;
  const f16* gB1a = gB0a + 128 * K;
  const f16* gB1b = gB0b + 128 * K;

#define STAGE_P(G0, G1, EOFF, LB, MAT, H)                                      \
  { GLOAD16((G0) + (EOFF), &lds[LB][MAT][H][wid * 512]);                       \
    GLOAD16((G1) + (EOFF), &lds[LB][MAT][H][4096 + wid * 512]); }

  const int lane_rd = (((l & 15) << 6) + ((l >> 4) << 4)) ^ (((l >> 3) & 1) << 5);
  const char* rdA0 = (const char*)&lds[0][0][wr][0] + lane_rd;
  const char* rdA1 = (const char*)&lds[1][0][wr][0] + lane_rd;
  const char* rdB0 = (const char*)&lds[0][1][wc >> 1][0] + (wc & 1) * 8192 + lane_rd;
  const char* rdB1 = (const char*)&lds[1][1][wc >> 1][0] + (wc & 1) * 8192 + lane_rd;

  f16x8 af[4][2], bf0[2][2], bf1[2][2];
  f32x4 acc[8][4] = {};

#define READ_A_MH(RD, mh)                                                      \
  _Pragma("unroll") for (int mm = 0; mm < 4; ++mm)                             \
  _Pragma("unroll") for (int ks = 0; ks < 2; ++ks)                             \
    af[mm][ks] = *reinterpret_cast<const f16x8*>(                              \
        (RD) + (((((mh)*4 + mm) * 2) + ks) << 10));
#define READ_B_NH(DST, RD, nh)                                                 \
  _Pragma("unroll") for (int nn = 0; nn < 2; ++nn)                             \
  _Pragma("unroll") for (int ks = 0; ks < 2; ++ks)                             \
    DST[nn][ks] = *reinterpret_cast<const f16x8*>(                             \
        (RD) + (((((nh)*2 + nn) * 2) + ks) << 10));
#define CL2(BF, mh, nh)                                                        \
  __builtin_amdgcn_s_setprio(1);                                               \
  _Pragma("unroll") for (int mm = 0; mm < 4; ++mm)                             \
  _Pragma("unroll") for (int nn = 0; nn < 2; ++nn)                             \
  _Pragma("unroll") for (int ks = 0; ks < 2; ++ks)                             \
    acc[(mh)*4 + mm][(nh)*2 + nn] =                                            \
        MFMA16(af[mm][ks], BF[nn][ks], acc[(mh)*4 + mm][(nh)*2 + nn]);         \
  __builtin_amdgcn_s_setprio(0);

  STAGE_P(gB0a, gB0b, 0, 0, 1, 0);
  STAGE_P(gB1a, gB1b, 0, 0, 1, 1);
  STAGE_P(gA0a, gA0b, 0, 0, 0, 0);
  STAGE_P(gA1a, gA1b, 0, 0, 0, 1);
  STAGE_P(gB0a, gB0b, 64, 1, 1, 0);
  STAGE_P(gB1a, gB1b, 64, 1, 1, 1);
  STAGE_P(gA0a, gA0b, 64, 1, 0, 0);
  VMW6();
  BARR();
  READ_A_MH(rdA0, 0);
  READ_B_NH(bf0, rdB0, 0);

  for (int i = 0; i < 8; ++i) {
    const bool more = (i < 7);
    STAGE_P(gA1a, gA1b, 64, 1, 0, 1);
    BARR();
    CL2(bf0, 0, 0);
    READ_B_NH(bf1, rdB0, 1);
    BARR();
    BARR();
    CL2(bf1, 0, 1);
    READ_A_MH(rdA0, 1);
    BARR();
    if (more) STAGE_P(gB0a, gB0b, 128, 0, 1, 0);
    BARR();
    CL2(bf1, 1, 1);
    if (more) { VMW2(); } else { VMW0(); }
    BARR();
    if (more) { STAGE_P(gB1a, gB1b, 128, 0, 1, 1); STAGE_P(gA0a, gA0b, 128, 0, 0, 0); }
    BARR();
    CL2(bf0, 1, 0);
    READ_A_MH(rdA1, 0);
    READ_B_NH(bf0, rdB1, 0);
    BARR();
    if (more) STAGE_P(gA1a, gA1b, 128, 0, 0, 1);
    BARR();
    CL2(bf0, 0, 0);
    READ_B_NH(bf1, rdB1, 1);
    BARR();
    BARR();
    CL2(bf1, 0, 1);
    READ_A_MH(rdA1, 1);
    BARR();
    if (more) STAGE_P(gB0a, gB0b, 192, 1, 1, 0);
    BARR();
    CL2(bf1, 1, 1);
    if (more) VMW2();
    BARR();
    if (more) { STAGE_P(gB1a, gB1b, 192, 1, 1, 1); STAGE_P(gA0a, gA0b, 192, 1, 0, 0); }
    BARR();
    CL2(bf0, 1, 0);
    if (more) { READ_A_MH(rdA0, 0); READ_B_NH(bf0, rdB0, 0); }
    BARR();
    gA0a += 128; gA0b += 128; gA1a += 128; gA1b += 128;
    gB0a += 128; gB0b += 128; gB1a += 128; gB1b += 128;
  }

  const int rr = by * 256 + wr * 128 + ((l >> 4) << 2);
  const int cc = bx * 256 + wc * 64 + (l & 15);
#pragma unroll
  for (int m = 0; m < 8; ++m)
#pragma unroll
    for (int n = 0; n < 4; ++n)
#pragma unroll
      for (int j = 0; j < 4; ++j)
        C[(size_t)(rr + m * 16 + j) * N + cc + n * 16] = (OutT)acc[m][n][j];
#undef STAGE_P
#undef READ_A_MH
#undef READ_B_NH
#undef CL2
}

// ---------------- scores: partial K-reduction (16 segments of 256 y) ----------------
__global__ __launch_bounds__(256, 2) void scores_part(const f16* __restrict__ qkv,
                                                      f16* __restrict__ part) {
  const int seg = blockIdx.x;            // 0..15
  const int bh = blockIdx.y;             // 0..127
  const int b = bh >> 4, h = bh & 15;
  const f16* base = qkv + (size_t)b * 4096 * 3072 + h * 64;   // Q; K at +1024

  __shared__ f16 sQ[64 * 264];
  __shared__ f16 sK[64 * 264];

  const int tid = threadIdx.x;
  const int w = tid >> 6, l = tid & 63;

  const int tsel = w >> 1;
  const int g = ((w & 1) << 6) + l;
  const int r0 = g >> 1;
  const int ch = g & 1;
  const f16* src = base + tsel * 1024 + (size_t)(seg * 256 + r0) * 3072 + ch * 32;
  f16* dstL = (tsel ? sK : sQ) + (ch * 32) * 264 + r0;

#pragma unroll
  for (int rep = 0; rep < 4; ++rep) {
    const f16* s0 = src + (size_t)(rep * 64) * 3072;
    f16x8 v0 = *reinterpret_cast<const f16x8*>(s0);
    f16x8 v1 = *reinterpret_cast<const f16x8*>(s0 + 8);
    f16x8 v2 = *reinterpret_cast<const f16x8*>(s0 + 16);
    f16x8 v3 = *reinterpret_cast<const f16x8*>(s0 + 24);
    f16* d = dstL + rep * 64;
#pragma unroll
    for (int j = 0; j < 8; ++j) {
      d[j * 264] = v0[j];
      d[(8 + j) * 264] = v1[j];
      d[(16 + j) * 264] = v2[j];
      d[(24 + j) * 264] = v3[j];
    }
  }
  __syncthreads();

  f32x4 acc[4] = {};
#pragma unroll
  for (int ys = 0; ys < 8; ++ys) {
    f16x8 a = *reinterpret_cast<const f16x8*>(sK + (w * 16 + (l & 15)) * 264 + ys * 32 + ((l >> 4) << 3));
#pragma unroll
    for (int n = 0; n < 4; ++n) {
      f16x8 bq = *reinterpret_cast<const f16x8*>(sQ + (n * 16 + (l & 15)) * 264 + ys * 32 + ((l >> 4) << 3));
      acc[n] = MFMA16(a, bq, acc[n]);
    }
  }

  f16* dst = part + ((size_t)(bh * 16 + seg)) * 4096;
#pragma unroll
  for (int n = 0; n < 4; ++n)
#pragma unroll
    for (int j = 0; j < 4; ++j)
      dst[(w * 16 + ((l >> 4) << 2) + j) * 64 + n * 16 + (l & 15)] = (f16)(acc[n][j] * 0.125f);
}

// ---------------- scores: combine partials + softmax -> Z^T ----------------
__global__ __launch_bounds__(256) void scores_combine(const f16* __restrict__ part,
                                                      f16* __restrict__ zt) {
  const int bh = blockIdx.x;
  const int kd = threadIdx.x >> 2;
  const int qg = threadIdx.x & 3;
  const f16* p0 = part + (size_t)bh * 16 * 4096 + kd * 64 + qg * 16;
  float s[16];
#pragma unroll
  for (int j = 0; j < 16; ++j) s[j] = 0.f;
#pragma unroll 4
  for (int seg = 0; seg < 16; ++seg) {
    f16x8 a = *reinterpret_cast<const f16x8*>(p0 + seg * 4096);
    f16x8 c = *reinterpret_cast<const f16x8*>(p0 + seg * 4096 + 8);
#pragma unroll
    for (int j = 0; j < 8; ++j) { s[j] += (float)a[j]; s[8 + j] += (float)c[j]; }
  }
  float mx = s[0];
#pragma unroll
  for (int j = 1; j < 16; ++j) mx = fmaxf(mx, s[j]);
  mx = fmaxf(mx, __shfl_xor(mx, 1));
  mx = fmaxf(mx, __shfl_xor(mx, 2));
  float sum = 0.f;
#pragma unroll
  for (int j = 0; j < 16; ++j) { float e = __expf(s[j] - mx); s[j] = e; sum += e; }
  sum += __shfl_xor(sum, 1);
  sum += __shfl_xor(sum, 2);
  float inv = 1.f / sum;
  f16* dst = zt + (size_t)bh * 4096 + (qg * 16) * 64 + kd;
#pragma unroll
  for (int j = 0; j < 16; ++j) dst[j * 64] = (f16)(s[j] * inv);
}

// ---------------- PV + head merge ----------------
__global__ __launch_bounds__(256, 2) void pv_merge(const f16* __restrict__ qkv,
                                                   const f16* __restrict__ zt,
                                                   f16* __restrict__ out2) {
  const int st = blockIdx.x;
  const int bh = blockIdx.y;
  const int b = bh >> 4, h = bh & 15;
  const f16* vg = qkv + (size_t)(b * 4096 + st * 128) * 3072 + 2048 + h * 64;

  __shared__ f16 sV[128 * 72];
  __shared__ f16 sZ[64 * 72];

  const int tid = threadIdx.x;
  const int w = tid >> 6, l = tid & 63;

#pragma unroll
  for (int p = 0; p < 4; ++p) {
    int idx = (p * 256 + tid) * 8;
    int row = idx >> 6, col = idx & 63;
    f16x8 v = *reinterpret_cast<const f16x8*>(vg + (size_t)row * 3072 + col);
    *reinterpret_cast<f16x8*>(sV + row * 72 + col) = v;
  }
#pragma unroll
  for (int p = 0; p < 2; ++p) {
    int idx = (p * 256 + tid) * 8;
    int row = idx >> 6, col = idx & 63;
    f16x8 v = *reinterpret_cast<const f16x8*>(zt + (size_t)bh * 4096 + idx);
    *reinterpret_cast<f16x8*>(sZ + row * 72 + col) = v;
  }
  __syncthreads();

  f32x4 acc[2][4] = {};
#pragma unroll
  for (int ks = 0; ks < 2; ++ks) {
    f16x8 av[2], bz[4];
#pragma unroll
    for (int m = 0; m < 2; ++m)
      av[m] = *reinterpret_cast<const f16x8*>(sV + (w * 32 + m * 16 + (l & 15)) * 72 + ks * 32 + ((l >> 4) << 3));
#pragma unroll
    for (int n = 0; n < 4; ++n)
      bz[n] = *reinterpret_cast<const f16x8*>(sZ + (n * 16 + (l & 15)) * 72 + ks * 32 + ((l >> 4) << 3));
#pragma unroll
    for (int m = 0; m < 2; ++m)
#pragma unroll
      for (int n = 0; n < 4; ++n)
        acc[m][n] = MFMA16(av[m], bz[n], acc[m][n]);
  }

#pragma unroll
  for (int m = 0; m < 2; ++m)
#pragma unroll
    for (int n = 0; n < 4; ++n)
#pragma unroll
      for (int j = 0; j < 4; ++j) {
        int s = st * 128 + w * 32 + m * 16 + ((l >> 4) << 2) + j;
        out2[(size_t)(b * 4096 + s) * 1024 + h * 64 + n * 16 + (l & 15)] = (f16)acc[m][n][j];
      }
}

// ---------------- launch ----------------
extern "C" void kernel_launch(void* const* d_in, const int* in_sizes, int n_in,
                              void* d_out, int out_size, void* d_ws, size_t ws_size,
                              hipStream_t stream) {
  const float* x  = (const float*)d_in[0];
  const float* Wq = (const float*)d_in[1];
  const float* Wk = (const float*)d_in[2];
  const float* Wv = (const float*)d_in[3];
  const float* Wo = (const float*)d_in[4];
  float* out = (float*)d_out;

  f16* xh    = (f16*)d_ws;               //  33,554,432  x (f16); dead after QKV GEMM
  f16* qkvh  = xh + 33554432;            // 100,663,296  [32768 x 3072] q|k|v
  f16* wqkvh = qkvh + 100663296;         //   3,145,728  [3072 x 1024]
  f16* woh   = wqkvh + 3145728;          //   1,048,576  [1024 x 1024]
  f16* zth   = woh + 1048576;            //     524,288  [128][64 zq][64 kd]
  f16* out2h = zth + 524288;             //  33,554,432  [32768 x 1024] merged
  f16* part  = (f16*)d_ws;               // 16.8 MB f16 partial scores — reuses dead xh

  cast_f32_to_f16<<<32768, 256, 0, stream>>>(x, xh, 33554432 / 4);
  cast_weights<<<4096, 256, 0, stream>>>(Wq, Wk, Wv, Wo, wqkvh, woh);

  // QKV projection: [32768,3072] = xh * Wqkv^T  (2048 blocks of 768thr, %8==0, bx fast)
  gemm_qkv_12w<<<2048, 768, 0, stream>>>(xh, wqkvh, qkvh, 3072, 16);

  // scores: 16-way split K-reduction, then combine + softmax
  scores_part<<<dim3(16, 128), 256, 0, stream>>>(qkvh, part);
  scores_combine<<<128, 256, 0, stream>>>(part, zth);

  pv_merge<<<dim3(32, 128), 256, 0, stream>>>(qkvh, zth, out2h);

  // output projection: d_out = out2 * Wo^T (f32 out)   (512 blocks, %8==0, bx fast)
  gemm_bt_8ph<float><<<128 * 4, 512, 0, stream>>>(out2h, woh, out, 1024, 4);
}